// Round 8
// baseline (185.865 us; speedup 1.0000x reference)
//
#include <hip/hip_runtime.h>
#include <hip/hip_bf16.h>

// MetaConv2d fused hypernetwork + dynamic conv, bf16 MFMA. Round 8.
// out[bn,t,o] = sum_{c,k} x[bn,t+k,c] * w[bn,o,c,k] + bias[bn,o]
//   w[bn,p]   = meta[bn,:]·w_lin_w[p,:] + w_lin_b[p],  p = o*192 + c*3 + k
//
// KEY CHANGE vs r6/r7: 512-thread blocks (8 waves, 1 wave = 1 node, NT=8),
// static LDS 63.6 KB, <=128 VGPR  ->  TWO independent blocks per CU.
// r6/r7 had one 16-wave barrier-locked block per CU: every barrier/L2-latency
// window idled the whole CU. Two phase-shifted blocks fill each other's stalls
// (m114: independent waves on a CU overlap fully).
//
// Per block: 8 phases = 2 c-chunks(32) x 4 o-quarters(16).
//   hyper: 12 MFMA-tiles/wave (2 o-rows x 2 ch x 3 k) -> w LDS (single buffer)
//   conv : 3 B + 12 A ds_reads, 12 MFMA into acc[4][4] (all static idx)
//   2 barriers/phase. x c-chunk staged in a single 34 KB buffer (XSTR=34
//   shorts = 17 dwords, odd -> conflict-free A-reads); chunk-1 restage hidden
//   inside phase (cc=1,oq=0) after hyper's loads are issued.

#define BN_TOT   8192
#define C_IN     64
#define C_OUT    64
#define M_DIM    32
#define S_OUT    62

#define NT       8            // nodes per block = waves per block
#define NTHREADS 512          // 8 waves
#define XSTR     34           // shorts per x row (32 c + 2 pad): 17 dw, odd
#define XNODE    (64 * XSTR)  // 2176 shorts per node
#define XBUFN    (NT * XNODE) // 17408 shorts = 34816 B
#define OSTR     104          // shorts per o-row in w (96 j + 8 pad)
#define WNODE    (16 * OSTR + 8)   // 1672 shorts (o-quarter: 16 o-rows)
#define WBUFN    (NT * WNODE)      // 13376 shorts = 26752 B
#define WLW_ROWS 12288
#define WS_NEED  (WLW_ROWS * M_DIM * 2 + WLW_ROWS * 4)

typedef __attribute__((ext_vector_type(8))) short bf16x8;
typedef __attribute__((ext_vector_type(4))) float f32x4;

static __device__ __forceinline__ short f2bf(float f) {
    return __bfloat16_as_short(__float2bfloat16(f));
}

static __device__ __forceinline__ bf16x8 cvt8(float4 a, float4 b) {
    bf16x8 r;
    r[0] = f2bf(a.x); r[1] = f2bf(a.y); r[2] = f2bf(a.z); r[3] = f2bf(a.w);
    r[4] = f2bf(b.x); r[5] = f2bf(b.y); r[6] = f2bf(b.z); r[7] = f2bf(b.w);
    return r;
}

// ---------------- pre-pass 1: w_lin_w f32 -> bf16 ----------------
extern "C" __global__ void wlw_to_bf16(const float* __restrict__ src,
                                       short* __restrict__ dst) {
    const int i = (blockIdx.x * 256 + threadIdx.x) * 8;
    const float4 a = *reinterpret_cast<const float4*>(src + i);
    const float4 b = *reinterpret_cast<const float4*>(src + i + 4);
    *reinterpret_cast<bf16x8*>(dst + i) = cvt8(a, b);
}

// ---------------- pre-pass 2: wlb -> wlbR[o][k][c] f32 ----------------
extern "C" __global__ void wlb_rearr(const float* __restrict__ wlb,
                                     float* __restrict__ wlbR) {
    const int i = blockIdx.x * 256 + threadIdx.x;
    const int o = i / 192;
    const int r = i - o * 192;
    const int k = r >> 6;
    const int c = r & 63;
    wlbR[i] = wlb[o * 192 + c * 3 + k];
}

// ---------------- fused kernel ----------------
template <int USE_WS>
__global__ void __launch_bounds__(NTHREADS, 4)   // 4 waves/SIMD -> 2 blocks/CU
metaconv_fused(const float* __restrict__ meta,   // [8192][32]
               const float* __restrict__ x,      // [8192][64][64]
               const float* __restrict__ wlw,    // [12288][32] f32
               const short* __restrict__ wlwbf,  // [12288][32] bf16 (ws)
               const float* __restrict__ wlb,    // [12288]
               const float* __restrict__ wlbR,   // [64][3][64] (ws)
               const float* __restrict__ blw,    // [64][32]
               const float* __restrict__ blb,    // [64]
               float* __restrict__ out)          // [8192][62][64]
{
    __shared__ short xsh[XBUFN];          // current c-chunk, [node][row][34]
    __shared__ short wsh[WBUFN];          // current o-quarter w, [node][16 o][OSTR]
    __shared__ float bias_s[NT][C_OUT];

    const int tid  = threadIdx.x;
    const int wave = tid >> 6;            // 0..7 == node
    const int lane = tid & 63;
    const int l16  = lane & 15;
    const int g    = lane >> 4;
    const int bn0  = blockIdx.x * NT;

    const float* xsrc = x + (size_t)(bn0 + wave) * (64 * C_IN);

    // stage one 32-wide c-chunk of this wave's node: 8 float4 loads/lane
    auto stage_x = [&](int c0) {
        short* xd = xsh + wave * XNODE;
        #pragma unroll
        for (int i = 0; i < 4; ++i) {
            const int gid = i * 64 + lane;        // 256 granules = 64 rows x 4
            const int row = gid >> 2;
            const int gr  = gid & 3;
            const float* p = xsrc + row * 64 + c0 + gr * 8;
            const float4 a = *reinterpret_cast<const float4*>(p);
            const float4 b = *reinterpret_cast<const float4*>(p + 4);
            *reinterpret_cast<bf16x8*>(xd + row * XSTR + gr * 8) = cvt8(a, b);
        }
    };

    // per-block bias table: exactly one (node,o) per thread (8*64 == 512)
    {
        const int bnode = tid >> 6;
        const int o     = tid & 63;
        const float* mrow = meta + (size_t)(bn0 + bnode) * M_DIM;
        const float* brow = blw + o * M_DIM;
        float s = blb[o];
        #pragma unroll
        for (int m = 0; m < M_DIM; ++m) s += mrow[m] * brow[m];
        bias_s[bnode][o] = s;
    }

    // meta B-fragment (cols = nodes, 8..15 duplicate -> discarded on write)
    bf16x8 metaF;
    {
        const float* mp = meta + (size_t)(bn0 + (l16 & (NT - 1))) * M_DIM + g * 8;
        metaF = cvt8(*reinterpret_cast<const float4*>(mp),
                     *reinterpret_cast<const float4*>(mp + 4));
    }

    // hyper for one phase (c-chunk c0, o-quarter oq): 12 tiles/wave as 2x6.
    // D lane(l16,g): col=node=l16 (valid l16<8), rows cc_local = ch*16+g*4+r.
    auto hyper = [&](int c0, int oq) {
        #pragma unroll 1
        for (int ou = 0; ou < 2; ++ou) {
            const int o_l = wave * 2 + ou;        // 0..15 within quarter
            const int og  = oq * 16 + o_l;        // global o
            #pragma unroll
            for (int ch = 0; ch < 2; ++ch) {
                #pragma unroll
                for (int k = 0; k < 3; ++k) {
                    const int pr = og * 192 + (c0 + ch * 16 + l16) * 3 + k;
                    bf16x8 aF;
                    f32x4 Cf;
                    if constexpr (USE_WS) {
                        aF = *reinterpret_cast<const bf16x8*>(wlwbf + (size_t)pr * M_DIM + g * 8);
                        const float4 cf = *reinterpret_cast<const float4*>(
                            wlbR + (og * 3 + k) * 64 + c0 + ch * 16 + g * 4);
                        Cf[0] = cf.x; Cf[1] = cf.y; Cf[2] = cf.z; Cf[3] = cf.w;
                    } else {
                        const float* wp = wlw + (size_t)pr * M_DIM + g * 8;
                        aF = cvt8(*reinterpret_cast<const float4*>(wp),
                                  *reinterpret_cast<const float4*>(wp + 4));
                        const int cb = c0 + ch * 16 + g * 4;
                        const int pb = og * 192 + k;
                        Cf[0] = wlb[pb + (cb + 0) * 3];
                        Cf[1] = wlb[pb + (cb + 1) * 3];
                        Cf[2] = wlb[pb + (cb + 2) * 3];
                        Cf[3] = wlb[pb + (cb + 3) * 3];
                    }
                    const f32x4 d = __builtin_amdgcn_mfma_f32_16x16x32_bf16(aF, metaF, Cf, 0, 0, 0);
                    if (l16 < NT) {
                        const int off = l16 * WNODE + o_l * OSTR + k * 32 + ch * 16 + g * 4;
                        *reinterpret_cast<short4*>(&wsh[off]) =
                            make_short4(f2bf(d[0]), f2bf(d[1]), f2bf(d[2]), f2bf(d[3]));
                    }
                }
            }
        }
    };

    const f32x4 ZV = {0.f, 0.f, 0.f, 0.f};
    f32x4 acc[4][4];                      // [t-tile][o-quarter] — static idx only
    #pragma unroll
    for (int t = 0; t < 4; ++t)
        #pragma unroll
        for (int o = 0; o < 4; ++o) acc[t][o] = ZV;

    // prologue: stage chunk 0 (bias/metaF above overlap the loads)
    stage_x(0);
    __syncthreads();

    #pragma unroll
    for (int cc = 0; cc < 2; ++cc) {
        const int c0 = cc * 32;
        #pragma unroll
        for (int oq = 0; oq < 4; ++oq) {
            // ---- producer half: hyper (+ chunk-1 restage hidden here) ----
            hyper(c0, oq);
            if (cc == 1 && oq == 0) stage_x(32);   // xsh free since barrier; loads
                                                   // overlap hyper's L2 stream
            __syncthreads();                       // w (and x) ready

            // ---- consumer half: conv, 12 MFMA into acc[.][oq] ----
            const short* wn = wsh + wave * WNODE;
            const short* xn = xsh + wave * XNODE;
            bf16x8 B[3];
            #pragma unroll
            for (int k = 0; k < 3; ++k)
                B[k] = *reinterpret_cast<const bf16x8*>(wn + l16 * OSTR + k * 32 + g * 8);
            #pragma unroll
            for (int ttl = 0; ttl < 4; ++ttl) {
                #pragma unroll
                for (int k = 0; k < 3; ++k) {
                    int row = ttl * 16 + l16 + k;
                    row = row < 63 ? row : 63;     // only discarded t>=62 clamp
                    const bf16x8 A = *reinterpret_cast<const bf16x8*>(
                        xn + row * XSTR + g * 8);
                    acc[ttl][oq] = __builtin_amdgcn_mfma_f32_16x16x32_bf16(
                        A, B[k], acc[ttl][oq], 0, 0, 0);
                }
            }
            __syncthreads();                       // conv done before next hyper
        }
    }

    // ---------------- epilogue: add bias, store f32 ----------------
    float* ob = out + (size_t)(bn0 + wave) * (S_OUT * C_OUT);
    #pragma unroll
    for (int ttl = 0; ttl < 4; ++ttl) {
        #pragma unroll
        for (int ot = 0; ot < 4; ++ot) {
            const int o  = ot * 16 + l16;
            const float bv = bias_s[wave][o];
            #pragma unroll
            for (int r = 0; r < 4; ++r) {
                const int t = ttl * 16 + g * 4 + r;
                if (t < S_OUT) ob[t * C_OUT + o] = acc[ttl][ot][r] + bv;
            }
        }
    }
}

extern "C" void kernel_launch(void* const* d_in, const int* in_sizes, int n_in,
                              void* d_out, int out_size, void* d_ws, size_t ws_size,
                              hipStream_t stream) {
    const float* meta = (const float*)d_in[0];
    const float* x    = (const float*)d_in[1];
    const float* wlw  = (const float*)d_in[2];
    const float* wlb  = (const float*)d_in[3];
    const float* blw  = (const float*)d_in[4];
    const float* blb  = (const float*)d_in[5];
    float* out = (float*)d_out;
    (void)in_sizes; (void)n_in; (void)out_size;

    short* wlwbf = (short*)d_ws;
    float* wlbR  = (float*)((char*)d_ws + (size_t)WLW_ROWS * M_DIM * 2);

    if (ws_size >= (size_t)WS_NEED) {
        wlw_to_bf16<<<dim3(WLW_ROWS * M_DIM / (256 * 8)), dim3(256), 0, stream>>>(wlw, wlwbf);
        wlb_rearr<<<dim3(WLW_ROWS / 256), dim3(256), 0, stream>>>(wlb, wlbR);
        metaconv_fused<1><<<dim3(BN_TOT / NT), dim3(NTHREADS), 0, stream>>>(
            meta, x, wlw, wlwbf, wlb, wlbR, blw, blb, out);
    } else {
        metaconv_fused<0><<<dim3(BN_TOT / NT), dim3(NTHREADS), 0, stream>>>(
            meta, x, wlw, wlwbf, wlb, wlbR, blw, blb, out);
    }
}

// Round 9
// 165.748 us; speedup vs baseline: 1.1214x; 1.1214x over previous
//
#include <hip/hip_runtime.h>
#include <hip/hip_bf16.h>

// MetaConv2d fused hypernetwork + dynamic conv, bf16 MFMA. Round 9.
// out[bn,t,o] = sum_{c,k} x[bn,t+k,c] * w[bn,o,c,k] + bias[bn,o]
//   w[bn,p]   = meta[bn,:]·w_lin_w[p,:] + w_lin_b[p],  p = o*192 + c*3 + k
//
// Block = 8 nodes, 1024 threads (16 waves = 8 nodes x 2 t-halves), grid 1024.
// KEY CHANGE vs r6 (best, 143us): x LDS round-trip ELIMINATED. Conv A-fragments
// load directly global->reg (per-wave 4KB working set, L1-resident across the
// 3 k-shifted re-reads), held across the 4 oq phases of each c-chunk.
// w is double-buffered; ONE barrier per phase, 8 finer phases (2 cc x 4 oq):
//   P: [P==0/4: load+cvt 6 A-frags (2 groups of 6 loads, r3-proven depth)]
//      hyper(P+1) -> wbuf[(P+1)&1]   (6 tiles/wave: 1 o-row x 2 ch x 3 k)
//      conv(P)    <- wbuf[P&1]       (3 B ds_reads + 6 MFMA, A in regs)
//      __syncthreads()
// LDS: static 55.5 KB = w 2 x 26.1 KB + bias 2 KB. All acc indices static.

#define BN_TOT   8192
#define C_IN     64
#define C_OUT    64
#define M_DIM    32
#define S_OUT    62

#define NT       8            // nodes per block
#define NTHREADS 1024         // 16 waves
#define OSTR     104          // shorts per o-row in w (96 j + 8 pad)
#define WNODE    (16 * OSTR + 8)   // 1672 shorts (one o-quarter: 16 o-rows)
#define WBUF     (NT * WNODE)      // 13376 shorts = 26752 B per buffer
#define WLW_ROWS 12288
#define WS_NEED  (WLW_ROWS * M_DIM * 2 + WLW_ROWS * 4)

typedef __attribute__((ext_vector_type(8))) short bf16x8;
typedef __attribute__((ext_vector_type(4))) float f32x4;

static __device__ __forceinline__ short f2bf(float f) {
    return __bfloat16_as_short(__float2bfloat16(f));
}

static __device__ __forceinline__ bf16x8 cvt8(float4 a, float4 b) {
    bf16x8 r;
    r[0] = f2bf(a.x); r[1] = f2bf(a.y); r[2] = f2bf(a.z); r[3] = f2bf(a.w);
    r[4] = f2bf(b.x); r[5] = f2bf(b.y); r[6] = f2bf(b.z); r[7] = f2bf(b.w);
    return r;
}

// ---------------- pre-pass 1: w_lin_w f32 -> bf16 ----------------
extern "C" __global__ void wlw_to_bf16(const float* __restrict__ src,
                                       short* __restrict__ dst) {
    const int i = (blockIdx.x * 256 + threadIdx.x) * 8;
    const float4 a = *reinterpret_cast<const float4*>(src + i);
    const float4 b = *reinterpret_cast<const float4*>(src + i + 4);
    *reinterpret_cast<bf16x8*>(dst + i) = cvt8(a, b);
}

// ---------------- pre-pass 2: wlb -> wlbR[o][k][c] f32 ----------------
extern "C" __global__ void wlb_rearr(const float* __restrict__ wlb,
                                     float* __restrict__ wlbR) {
    const int i = blockIdx.x * 256 + threadIdx.x;
    const int o = i / 192;
    const int r = i - o * 192;
    const int k = r >> 6;
    const int c = r & 63;
    wlbR[i] = wlb[o * 192 + c * 3 + k];
}

// ---------------- fused kernel ----------------
template <int USE_WS>
__global__ void __launch_bounds__(NTHREADS, 4)
metaconv_fused(const float* __restrict__ meta,   // [8192][32]
               const float* __restrict__ x,      // [8192][64][64]
               const float* __restrict__ wlw,    // [12288][32] f32
               const short* __restrict__ wlwbf,  // [12288][32] bf16 (ws)
               const float* __restrict__ wlb,    // [12288]
               const float* __restrict__ wlbR,   // [64][3][64] (ws)
               const float* __restrict__ blw,    // [64][32]
               const float* __restrict__ blb,    // [64]
               float* __restrict__ out)          // [8192][62][64]
{
    __shared__ short wsh[2 * WBUF];       // double-buffered w (o-quarter each)
    __shared__ float bias_s[NT][C_OUT];

    const int tid   = threadIdx.x;
    const int wave  = tid >> 6;           // 0..15
    const int lane  = tid & 63;
    const int l16   = lane & 15;
    const int g     = lane >> 4;
    const int node  = wave & (NT - 1);
    const int thalf = wave >> 3;
    const int bn0   = blockIdx.x * NT;

    const float* xsrc = x + (size_t)(bn0 + node) * (64 * C_IN);

    // per-block bias table (tid < 512)
    if (tid < NT * C_OUT) {
        const int bnode = tid >> 6;
        const int o     = tid & 63;
        const float* mrow = meta + (size_t)(bn0 + bnode) * M_DIM;
        const float* brow = blw + o * M_DIM;
        float s = blb[o];
        #pragma unroll
        for (int m = 0; m < M_DIM; ++m) s += mrow[m] * brow[m];
        bias_s[bnode][o] = s;
    }

    // meta B-fragment (cols = nodes, 8..15 duplicate -> discarded on write)
    bf16x8 metaF;
    {
        const float* mp = meta + (size_t)(bn0 + (l16 & (NT - 1))) * M_DIM + g * 8;
        metaF = cvt8(*reinterpret_cast<const float4*>(mp),
                     *reinterpret_cast<const float4*>(mp + 4));
    }

    // ---- conv A-fragments: global -> reg, one c-chunk at a time ----
    // A[ttl][k] lane(l16,g) holds x[thalf*32+ttl*16+l16+k][c0 + g*8 + e].
    bf16x8 Abf[2][3];
    auto load_A = [&](int c0) {
        #pragma unroll
        for (int ttl = 0; ttl < 2; ++ttl) {
            float4 ra[3], rb[3];
            #pragma unroll
            for (int k = 0; k < 3; ++k) {           // 6 loads in flight
                int row = thalf * 32 + ttl * 16 + l16 + k;
                row = row < 63 ? row : 63;           // t>=62 rows discarded later
                const float* p = xsrc + row * 64 + c0 + g * 8;
                ra[k] = *reinterpret_cast<const float4*>(p);
                rb[k] = *reinterpret_cast<const float4*>(p + 4);
            }
            #pragma unroll
            for (int k = 0; k < 3; ++k) Abf[ttl][k] = cvt8(ra[k], rb[k]);
        }
    };

    // hyper for one phase (c-chunk c0, o-quarter oq): 6 tiles/wave (o-row=wave).
    // D lane(l16,g): col=node=l16 (valid l16<8), rows cc_local = ch*16+g*4+r.
    auto hyper = [&](int c0, int oq, int buf) {
        const int og = oq * 16 + wave;              // global o (16 waves = quarter)
        short* wd = wsh + buf * WBUF;
        #pragma unroll
        for (int ch = 0; ch < 2; ++ch) {
            #pragma unroll
            for (int k = 0; k < 3; ++k) {
                const int pr = og * 192 + (c0 + ch * 16 + l16) * 3 + k;
                bf16x8 aF;
                f32x4 Cf;
                if constexpr (USE_WS) {
                    aF = *reinterpret_cast<const bf16x8*>(wlwbf + (size_t)pr * M_DIM + g * 8);
                    const float4 cf = *reinterpret_cast<const float4*>(
                        wlbR + (og * 3 + k) * 64 + c0 + ch * 16 + g * 4);
                    Cf[0] = cf.x; Cf[1] = cf.y; Cf[2] = cf.z; Cf[3] = cf.w;
                } else {
                    const float* wp = wlw + (size_t)pr * M_DIM + g * 8;
                    aF = cvt8(*reinterpret_cast<const float4*>(wp),
                              *reinterpret_cast<const float4*>(wp + 4));
                    const int cb = c0 + ch * 16 + g * 4;
                    const int pb = og * 192 + k;
                    Cf[0] = wlb[pb + (cb + 0) * 3];
                    Cf[1] = wlb[pb + (cb + 1) * 3];
                    Cf[2] = wlb[pb + (cb + 2) * 3];
                    Cf[3] = wlb[pb + (cb + 3) * 3];
                }
                const f32x4 d = __builtin_amdgcn_mfma_f32_16x16x32_bf16(aF, metaF, Cf, 0, 0, 0);
                if (l16 < NT) {
                    const int off = l16 * WNODE + wave * OSTR + k * 32 + ch * 16 + g * 4;
                    *reinterpret_cast<short4*>(&wd[off]) =
                        make_short4(f2bf(d[0]), f2bf(d[1]), f2bf(d[2]), f2bf(d[3]));
                }
            }
        }
    };

    const f32x4 ZV = {0.f, 0.f, 0.f, 0.f};
    f32x4 acc[2][4];                      // [t-tile local][oq] — static idx only
    #pragma unroll
    for (int t = 0; t < 2; ++t)
        #pragma unroll
        for (int o = 0; o < 4; ++o) acc[t][o] = ZV;

    // prologue: A-frags chunk 0 + hyper phase 0
    load_A(0);
    hyper(0, 0, 0);
    __syncthreads();

    #pragma unroll
    for (int cc = 0; cc < 2; ++cc) {
        #pragma unroll
        for (int oq = 0; oq < 4; ++oq) {
            const int P = cc * 4 + oq;
            if (P == 4) load_A(32);                 // chunk-1 A-frags (reg, 2x6 loads)
            if (P < 7) {
                const int Pn = P + 1;
                hyper((Pn >> 2) * 32, Pn & 3, Pn & 1);
            }
            // conv: 3 B ds_reads + 6 MFMA (A already in regs)
            const short* wn = wsh + (P & 1) * WBUF + node * WNODE;
            bf16x8 B[3];
            #pragma unroll
            for (int k = 0; k < 3; ++k)
                B[k] = *reinterpret_cast<const bf16x8*>(wn + l16 * OSTR + k * 32 + g * 8);
            #pragma unroll
            for (int ttl = 0; ttl < 2; ++ttl)
                #pragma unroll
                for (int k = 0; k < 3; ++k)
                    acc[ttl][oq] = __builtin_amdgcn_mfma_f32_16x16x32_bf16(
                        Abf[ttl][k], B[k], acc[ttl][oq], 0, 0, 0);
            __syncthreads();                        // hyper(P+1) writes done
        }
    }

    // ---------------- epilogue: add bias, store f32 ----------------
    float* ob = out + (size_t)(bn0 + node) * (S_OUT * C_OUT);
    #pragma unroll
    for (int ttl = 0; ttl < 2; ++ttl) {
        #pragma unroll
        for (int ot = 0; ot < 4; ++ot) {
            const int o  = ot * 16 + l16;
            const float bv = bias_s[node][o];
            #pragma unroll
            for (int r = 0; r < 4; ++r) {
                const int t = thalf * 32 + ttl * 16 + g * 4 + r;
                if (t < S_OUT) ob[t * C_OUT + o] = acc[ttl][ot][r] + bv;
            }
        }
    }
}

extern "C" void kernel_launch(void* const* d_in, const int* in_sizes, int n_in,
                              void* d_out, int out_size, void* d_ws, size_t ws_size,
                              hipStream_t stream) {
    const float* meta = (const float*)d_in[0];
    const float* x    = (const float*)d_in[1];
    const float* wlw  = (const float*)d_in[2];
    const float* wlb  = (const float*)d_in[3];
    const float* blw  = (const float*)d_in[4];
    const float* blb  = (const float*)d_in[5];
    float* out = (float*)d_out;
    (void)in_sizes; (void)n_in; (void)out_size;

    short* wlwbf = (short*)d_ws;
    float* wlbR  = (float*)((char*)d_ws + (size_t)WLW_ROWS * M_DIM * 2);

    if (ws_size >= (size_t)WS_NEED) {
        wlw_to_bf16<<<dim3(WLW_ROWS * M_DIM / (256 * 8)), dim3(256), 0, stream>>>(wlw, wlwbf);
        wlb_rearr<<<dim3(WLW_ROWS / 256), dim3(256), 0, stream>>>(wlb, wlbR);
        metaconv_fused<1><<<dim3(BN_TOT / NT), dim3(NTHREADS), 0, stream>>>(
            meta, x, wlw, wlwbf, wlb, wlbR, blw, blb, out);
    } else {
        metaconv_fused<0><<<dim3(BN_TOT / NT), dim3(NTHREADS), 0, stream>>>(
            meta, x, wlw, wlwbf, wlb, wlbR, blw, blb, out);
    }
}